// Round 17
// baseline (778.011 us; speedup 1.0000x reference)
//
#include <hip/hip_runtime.h>

// ---------------------------------------------------------------------------
// LoRA QKV: out_p = x @ (W_p + B_p @ A_p)^T  for p in {q,k,v}
// M = 8192, N = 4096 per proj (x3), K = 4096.
// Fold LoRA into weights (exact), bf16 convert (merged prep, LDS-shared A),
// fused 3-proj GEMM: 256x256 single-barrier 8-phase schedule, balanced
// 4/8/4/8 reads, split vm-guards. r17 = r16 + front-loaded 4-read phases
// with counted lgkmcnt(4) (LDS pipe fed during MFMA burst).
// ---------------------------------------------------------------------------

typedef __bf16 bf16x8 __attribute__((ext_vector_type(8)));
typedef float f32x4 __attribute__((ext_vector_type(4)));

#define GLL16(g, l)                                                        \
  __builtin_amdgcn_global_load_lds(                                        \
      (const __attribute__((address_space(1))) unsigned int*)(g),          \
      (__attribute__((address_space(3))) unsigned int*)(l), 16, 0, 0)

#define BAR()                                                              \
  {                                                                        \
    __builtin_amdgcn_sched_barrier(0);                                     \
    __builtin_amdgcn_s_barrier();                                          \
    __builtin_amdgcn_sched_barrier(0);                                     \
  }
// counted lgkm wait + sched fence (rule #18)
#define WLGS(n)                                                            \
  {                                                                        \
    asm volatile("s_waitcnt lgkmcnt(" #n ")" ::: "memory");                \
    __builtin_amdgcn_sched_barrier(0);                                     \
  }
#define WVM(n) asm volatile("s_waitcnt vmcnt(" #n ")" ::: "memory")

#define LDV(p) (*reinterpret_cast<const bf16x8*>(p))

// read 4 A-frags (m = M0..M0+3), both k-substeps, into dst[2][4]  (8 reads)
#define RDA(dst, base, M0)                                                 \
  _Pragma("unroll") for (int mm = 0; mm < 4; ++mm) {                       \
    dst[0][mm] = LDV((base) + ((M0) + mm) * 1024 + swk0);                  \
    dst[1][mm] = LDV((base) + ((M0) + mm) * 1024 + swk1);                  \
  }
// read 2 B-frags (n = N0..N0+1), both k-substeps, into dst[2][2]  (4 reads)
#define RDB(dst, base, N0)                                                 \
  _Pragma("unroll") for (int nn = 0; nn < 2; ++nn) {                       \
    dst[0][nn] = LDV((base) + ((N0) + nn) * 1024 + swk0);                  \
    dst[1][nn] = LDV((base) + ((N0) + nn) * 1024 + swk1);                  \
  }

// one C-quadrant x K=64: 16 MFMAs, ks outer => 8 independent chains (len 2)
#define MFQ(AQ, BQ, MB, NB)                                                \
  {                                                                        \
    __builtin_amdgcn_s_setprio(1);                                         \
    _Pragma("unroll") for (int ks = 0; ks < 2; ++ks)                       \
        _Pragma("unroll") for (int mm = 0; mm < 4; ++mm)                   \
            _Pragma("unroll") for (int nn = 0; nn < 2; ++nn)               \
                acc[(MB) + mm][(NB) + nn] =                                \
                    __builtin_amdgcn_mfma_f32_16x16x32_bf16(               \
                        AQ[ks][mm], BQ[ks][nn], acc[(MB) + mm][(NB) + nn], \
                        0, 0, 0);                                          \
    __builtin_amdgcn_s_setprio(0);                                         \
  }

// stage one 16KB half-tile (2 loads/thread). h = 128-row half, ko = K elem.
#define STG_A(db, h, ko)                                                   \
  {                                                                        \
    GLL16(sa + (size_t)((h)*128) * 4096 + (ko),                            \
          (char*)smem + (db)*65536 + (h)*16384 + tid * 16);                \
    GLL16(sa + (size_t)((h)*128 + 64) * 4096 + (ko),                       \
          (char*)smem + (db)*65536 + (h)*16384 + 8192 + tid * 16);         \
  }
#define STG_B(db, h, ko)                                                   \
  {                                                                        \
    GLL16(sb + (size_t)((h)*128) * 4096 + (ko),                            \
          (char*)smem + (db)*65536 + 32768 + (h)*16384 + tid * 16);        \
    GLL16(sb + (size_t)((h)*128 + 64) * 4096 + (ko),                       \
          (char*)smem + (db)*65536 + 32768 + (h)*16384 + 8192 + tid * 16); \
  }

__device__ __forceinline__ unsigned int f2b(float f) {
  unsigned int u = __builtin_bit_cast(unsigned int, f);
  u += 0x7FFFu + ((u >> 16) & 1u);
  return u >> 16;
}

// ---------------------------------------------------------------------------
// Prep (single launch; measured ~43us ~= roofline):
//  blocks [0, 8192):    convert x -> bf16 (16 elems/thread)
//  blocks [8192, 11264): fold W' = W + B@A with LDS-shared A-tiles
// ---------------------------------------------------------------------------
__global__ void prep_kernel(const float* __restrict__ x,
                            const float* __restrict__ w0,
                            const float* __restrict__ w1,
                            const float* __restrict__ w2,
                            const float* __restrict__ a0,
                            const float* __restrict__ b0,
                            const float* __restrict__ a1,
                            const float* __restrict__ b1,
                            const float* __restrict__ a2,
                            const float* __restrict__ b2,
                            unsigned short* __restrict__ xb,
                            unsigned short* __restrict__ wb) {
  __shared__ float As[16][512];  // 32 KB
  const int bid = blockIdx.x;
  const int tid = threadIdx.x;
  if (bid < 8192) {
    long base = ((long)bid * 256 + tid) * 2;
    const float4* xp = reinterpret_cast<const float4*>(x) + base * 2;
#pragma unroll
    for (int j = 0; j < 2; ++j) {
      float4 v0 = xp[2 * j];
      float4 v1 = xp[2 * j + 1];
      uint4 o;
      o.x = f2b(v0.x) | (f2b(v0.y) << 16);
      o.y = f2b(v0.z) | (f2b(v0.w) << 16);
      o.z = f2b(v1.x) | (f2b(v1.y) << 16);
      o.w = f2b(v1.z) | (f2b(v1.w) << 16);
      reinterpret_cast<uint4*>(xb)[base + j] = o;
    }
  } else {
    const int fb = bid - 8192;          // 0..3071
    const int proj = fb >> 10;          // 0..2
    const int rem = fb & 1023;
    const int h0 = (rem >> 3) * 32;
    const int d0b = (rem & 7) * 512;
    const float* W = (proj == 0) ? w0 : ((proj == 1) ? w1 : w2);
    const float* Amat = (proj == 0) ? a0 : ((proj == 1) ? a1 : a2);
    const float* Bmat = (proj == 0) ? b0 : ((proj == 1) ? b1 : b2);
    unsigned short* Wo = wb + (size_t)proj * 16777216UL;

#pragma unroll
    for (int j = 0; j < 8; ++j) {
      int idx4 = tid + j * 256;
      int row = idx4 >> 7;
      int col4 = idx4 & 127;
      float4 v = *reinterpret_cast<const float4*>(
          Amat + (size_t)row * 4096 + d0b + col4 * 4);
      *reinterpret_cast<float4*>(&As[row][col4 * 4]) = v;
    }
    __syncthreads();

    const int hl = tid >> 3;
    const int dl = (tid & 7) * 8;
    const int h = h0 + hl;
    float bv[16];
#pragma unroll
    for (int r = 0; r < 16; ++r) bv[r] = Bmat[h * 16 + r];

#pragma unroll
    for (int c = 0; c < 8; ++c) {
      const int d = dl + c * 64;
      const float4* wp =
          reinterpret_cast<const float4*>(W + (size_t)h * 4096 + d0b + d);
      float4 w0v = wp[0], w1v = wp[1];
      float acc[8] = {w0v.x, w0v.y, w0v.z, w0v.w,
                      w1v.x, w1v.y, w1v.z, w1v.w};
#pragma unroll
      for (int r = 0; r < 16; ++r) {
        const float4 A0 = *reinterpret_cast<const float4*>(&As[r][d]);
        const float4 A1 = *reinterpret_cast<const float4*>(&As[r][d + 4]);
        acc[0] += bv[r] * A0.x; acc[1] += bv[r] * A0.y;
        acc[2] += bv[r] * A0.z; acc[3] += bv[r] * A0.w;
        acc[4] += bv[r] * A1.x; acc[5] += bv[r] * A1.y;
        acc[6] += bv[r] * A1.z; acc[7] += bv[r] * A1.w;
      }
      uint4 o;
      o.x = f2b(acc[0]) | (f2b(acc[1]) << 16);
      o.y = f2b(acc[2]) | (f2b(acc[3]) << 16);
      o.z = f2b(acc[4]) | (f2b(acc[5]) << 16);
      o.w = f2b(acc[6]) | (f2b(acc[7]) << 16);
      *reinterpret_cast<uint4*>(Wo + (size_t)h * 4096 + d0b + d) = o;
    }
  }
}

// ---------------------------------------------------------------------------
// GEMM: 256x256 tile, single-barrier 8-phase, balanced 4/8/4/8 reads.
//   C[M, N*3] = Xb[M,K] @ Wb[3][N,K]^T
// 512 threads = 8 waves (2M x 4N), wave tile 128x64. BK=64 (2 x K32).
// LDS 128 KiB = 2 dbuf x { A: 2 x 16KB halves | B: 2 x 16KB }, XOR-swizzled.
//
// vs r16 (single variable, pure within-phase reorder, zero ledger change):
// the 4-read phases (ph1/3/5/7) issue their RDB at PHASE START, then wait
// with COUNTED lgkmcnt(4) -- drains exactly the previous phase's 8 reads
// (DS completes in-order per wave) while leaving own 4 in flight. The LDS
// pipe is fed during the MFMA burst instead of idling until after it.
// ph7 reads are st-gated, so its wait is st ? 4 : 0 (else the counted wait
// would leave prev-phase aHi reads undrained -> garbage).
//
// Collective safety + vmcnt ledger identical to r16 (proofs in r16 header):
// all reads after a barrier following all-waves' vm-guard of their region;
// all stages after a barrier following all-waves' lgkm-drain of the
// region's reads; guards WVM(4)@ph2/3/6/7 with 4-load groups; prologue
// drains T0 + collective BAR before first reads; tail i=31 WVM(0).
// ---------------------------------------------------------------------------
__global__ __launch_bounds__(512, 2) void gemm_kernel(
    const unsigned short* __restrict__ Xb,
    const unsigned short* __restrict__ Wb, float* __restrict__ out) {
  __shared__ unsigned short smem[65536];  // 128 KiB

  const int tid = threadIdx.x;
  const int lane = tid & 63;
  const int wid = tid >> 6;
  const int wm = wid >> 2;  // 0..1
  const int wn = wid & 3;   // 0..3

  int bid = blockIdx.x;                    // 1536 = 3 proj * 32 brow * 16 bcol
  int swz = (bid & 7) * 192 + (bid >> 3);  // bijective XCD swizzle
  int p = swz >> 9;
  int r = swz & 511;
  int brow = r >> 4;  // 0..31
  int bcol = r & 15;  // 0..15

  const unsigned short* GA = Xb + (size_t)brow * 256 * 4096;
  const unsigned short* GB =
      Wb + (size_t)p * 16777216UL + (size_t)bcol * 256 * 4096;

  // staging source, pre-swizzled so LDS[r][s] holds global[r][s^(r&7)]
  const int srow = tid >> 3;
  const int sslot = (tid & 7) ^ (srow & 7);
  const unsigned short* sa = GA + (size_t)srow * 4096 + sslot * 8;
  const unsigned short* sb = GB + (size_t)srow * 4096 + sslot * 8;

  // fragment-read bases (element units), swizzled k-slot offsets
  const int lrow = lane & 15;
  const int g = lane >> 4;  // 0..3
  const int swk0 = (g ^ (lane & 7)) * 8;
  const int swk1 = ((4 + g) ^ (lane & 7)) * 8;
  const __bf16* sm = (const __bf16*)smem;
  const __bf16* arA0 = sm + wm * 8192 + lrow * 64;
  const __bf16* arB0 =
      sm + 16384 + (wn >> 1) * 8192 + ((wn & 1) * 64 + lrow) * 64;
  const __bf16* arA1 = arA0 + 32768;
  const __bf16* arB1 = arB0 + 32768;

  f32x4 acc[8][4];
#pragma unroll
  for (int m = 0; m < 8; ++m)
#pragma unroll
    for (int n = 0; n < 4; ++n) acc[m][n] = {0.f, 0.f, 0.f, 0.f};

  bf16x8 aLo[2][4], aHi[2][4], bLoA[2][2], bLoB[2][2], bHi[2][2];

  // prologue: T0 full + T1.B (12 loads); own-drain T0; collective barrier;
  // then T0 q00 reads (aLo + bLoA) + T1.A stages (outstanding -> 8).
  STG_B(0, 0, 0); STG_B(0, 1, 0); STG_A(0, 0, 0); STG_A(0, 1, 0);
  STG_B(1, 0, 64); STG_B(1, 1, 64);
  WVM(4);  // own T0 landed; T1.B in flight
  BAR();   // ALL waves' T0 landed
  RDA(aLo, arA0, 0);
  RDB(bLoA, arB0, 0);
  STG_A(1, 0, 64); STG_A(1, 1, 64);  // out = T1.B(4) + T1.A(4) = 8

  for (int i = 0; i < 32; ++i) {
    const bool st = (i < 31);
    const size_t koN0 = (size_t)(2 * i + 2) * 64;
    const size_t koN1 = (size_t)(2 * i + 3) * 64;

    // ph1: read bHi(buf0) FIRST; counted wait drains prologue/ph8 reads;
    //      MFMA q00(buf0)                       [4 reads, front-loaded]
    BAR();
    RDB(bHi, arB0, 2);
    WLGS(4);
    MFQ(aLo, bLoA, 0, 0);
    // ph2: q01(buf0); read aHi(buf0); guard D1.B  [8 reads]
    BAR();
    WLGS(0);
    MFQ(aLo, bHi, 0, 2);
    RDA(aHi, arA0, 4);
    WVM(4);
    // ph3: read bLoB(buf1.B) FIRST (safe after BAR3); counted wait drains
    //      ph2's aHi; MFMA q11(buf0); stage N0.B; guard D1.A  [4 reads]
    BAR();
    RDB(bLoB, arB1, 0);
    WLGS(4);
    MFQ(aHi, bHi, 4, 2);
    if (st) {
      STG_B(0, 0, koN0);
      STG_B(0, 1, koN0);
      WVM(4);
    } else {
      WVM(0);
    }
    // ph4: q10(buf0); read aLo(buf1.A, safe after BAR4); stage N0.A [8 reads]
    BAR();
    WLGS(0);
    MFQ(aHi, bLoA, 4, 0);
    RDA(aLo, arA1, 0);
    if (st) {
      STG_A(0, 0, koN0);
      STG_A(0, 1, koN0);
    }
    // ph5: read bHi(buf1) FIRST; counted wait drains ph4's aLo;
    //      MFMA q00(buf1)                       [4 reads, front-loaded]
    BAR();
    RDB(bHi, arB1, 2);
    WLGS(4);
    MFQ(aLo, bLoB, 0, 0);
    // ph6: q01(buf1); read aHi(buf1); guard N0.B  [8 reads]
    BAR();
    WLGS(0);
    MFQ(aLo, bHi, 0, 2);
    RDA(aHi, arA1, 4);
    WVM(4);
    // ph7: read bLoA(buf0-next.B, safe after BAR7, st-gated) FIRST; counted
    //      wait (st?4:0) drains ph6's aHi; MFMA q11(buf1); stage N1.B
    BAR();
    if (st) {
      RDB(bLoA, arB0, 0);
      WLGS(4);
    } else {
      WLGS(0);
    }
    MFQ(aHi, bHi, 4, 2);
    if (st) {
      STG_B(1, 0, koN1);
      STG_B(1, 1, koN1);
      WVM(4);
    }
    // ph8: q10(buf1); read aLo(buf0-next.A); stage N1.A  [8 reads]
    BAR();
    WLGS(0);
    MFQ(aHi, bLoB, 4, 0);
    if (st) {
      RDA(aLo, arA0, 0);
      STG_A(1, 0, koN1);
      STG_A(1, 1, koN1);
    }
  }

  // epilogue: C/D layout col = lane&15, row = (lane>>4)*4 + q
  float* Cp = out + (size_t)p * 33554432UL +
              ((size_t)(brow * 256 + wm * 128 + g * 4)) * 4096 +
              (bcol * 256 + wn * 64 + lrow);
#pragma unroll
  for (int m = 0; m < 8; ++m)
#pragma unroll
    for (int q = 0; q < 4; ++q) {
      float* rp = Cp + (size_t)(m * 16 + q) * 4096;
#pragma unroll
      for (int n = 0; n < 4; ++n) rp[n * 16] = acc[m][n][q];
    }
}

// ---------------------------------------------------------------------------
extern "C" void kernel_launch(void* const* d_in, const int* in_sizes, int n_in,
                              void* d_out, int out_size, void* d_ws,
                              size_t ws_size, hipStream_t stream) {
  const float* x = (const float*)d_in[0];
  const float* wq = (const float*)d_in[1];
  const float* wk = (const float*)d_in[2];
  const float* wv = (const float*)d_in[3];
  const float* qa = (const float*)d_in[4];
  const float* qb = (const float*)d_in[5];
  const float* ka = (const float*)d_in[6];
  const float* kb = (const float*)d_in[7];
  const float* va = (const float*)d_in[8];
  const float* vb = (const float*)d_in[9];

  unsigned short* xb = (unsigned short*)d_ws;  // 67 MB
  unsigned short* wb = xb + 8192UL * 4096UL;   // 100 MB

  prep_kernel<<<11264, 256, 0, stream>>>(x, wq, wk, wv, qa, qb, ka, kb, va,
                                         vb, xb, wb);
  gemm_kernel<<<1536, 512, 0, stream>>>(xb, wb, (float*)d_out);
}

// Round 18
// 756.708 us; speedup vs baseline: 1.0282x; 1.0282x over previous
//
#include <hip/hip_runtime.h>

// ---------------------------------------------------------------------------
// LoRA QKV: out_p = x @ (W_p + B_p @ A_p)^T  for p in {q,k,v}
// M = 8192, N = 4096 per proj (x3), K = 4096.
// FINAL CONFIGURATION (= r16, best measured: 757us total, GEMM ~744us @
// ~1160 TF / 62% MfmaUtil, prep ~43us @ BW roofline, absmax 0.03125):
// fold LoRA into weights (exact), bf16 convert (merged prep, LDS-shared A),
// fused 3-proj GEMM: 256x256 single-barrier 8-phase schedule, balanced
// 4/8/4/8 reads, split vm-guards, XOR-swizzled LDS (0 bank conflicts),
// XCD-bijective block swizzle, mfma_f32_16x16x32_bf16.
// ---------------------------------------------------------------------------

typedef __bf16 bf16x8 __attribute__((ext_vector_type(8)));
typedef float f32x4 __attribute__((ext_vector_type(4)));

#define GLL16(g, l)                                                        \
  __builtin_amdgcn_global_load_lds(                                        \
      (const __attribute__((address_space(1))) unsigned int*)(g),          \
      (__attribute__((address_space(3))) unsigned int*)(l), 16, 0, 0)

#define BAR()                                                              \
  {                                                                        \
    __builtin_amdgcn_sched_barrier(0);                                     \
    __builtin_amdgcn_s_barrier();                                          \
    __builtin_amdgcn_sched_barrier(0);                                     \
  }
// counted lgkm wait + sched fence (rule #18)
#define WLGS(n)                                                            \
  {                                                                        \
    asm volatile("s_waitcnt lgkmcnt(" #n ")" ::: "memory");                \
    __builtin_amdgcn_sched_barrier(0);                                     \
  }
#define WVM(n) asm volatile("s_waitcnt vmcnt(" #n ")" ::: "memory")

#define LDV(p) (*reinterpret_cast<const bf16x8*>(p))

// read 4 A-frags (m = M0..M0+3), both k-substeps, into dst[2][4]  (8 reads)
#define RDA(dst, base, M0)                                                 \
  _Pragma("unroll") for (int mm = 0; mm < 4; ++mm) {                       \
    dst[0][mm] = LDV((base) + ((M0) + mm) * 1024 + swk0);                  \
    dst[1][mm] = LDV((base) + ((M0) + mm) * 1024 + swk1);                  \
  }
// read 2 B-frags (n = N0..N0+1), both k-substeps, into dst[2][2]  (4 reads)
#define RDB(dst, base, N0)                                                 \
  _Pragma("unroll") for (int nn = 0; nn < 2; ++nn) {                       \
    dst[0][nn] = LDV((base) + ((N0) + nn) * 1024 + swk0);                  \
    dst[1][nn] = LDV((base) + ((N0) + nn) * 1024 + swk1);                  \
  }

// one C-quadrant x K=64: 16 MFMAs, ks outer => 8 independent chains (len 2)
#define MFQ(AQ, BQ, MB, NB)                                                \
  {                                                                        \
    __builtin_amdgcn_s_setprio(1);                                         \
    _Pragma("unroll") for (int ks = 0; ks < 2; ++ks)                       \
        _Pragma("unroll") for (int mm = 0; mm < 4; ++mm)                   \
            _Pragma("unroll") for (int nn = 0; nn < 2; ++nn)               \
                acc[(MB) + mm][(NB) + nn] =                                \
                    __builtin_amdgcn_mfma_f32_16x16x32_bf16(               \
                        AQ[ks][mm], BQ[ks][nn], acc[(MB) + mm][(NB) + nn], \
                        0, 0, 0);                                          \
    __builtin_amdgcn_s_setprio(0);                                         \
  }

// stage one 16KB half-tile (2 loads/thread). h = 128-row half, ko = K elem.
#define STG_A(db, h, ko)                                                   \
  {                                                                        \
    GLL16(sa + (size_t)((h)*128) * 4096 + (ko),                            \
          (char*)smem + (db)*65536 + (h)*16384 + tid * 16);                \
    GLL16(sa + (size_t)((h)*128 + 64) * 4096 + (ko),                       \
          (char*)smem + (db)*65536 + (h)*16384 + 8192 + tid * 16);         \
  }
#define STG_B(db, h, ko)                                                   \
  {                                                                        \
    GLL16(sb + (size_t)((h)*128) * 4096 + (ko),                            \
          (char*)smem + (db)*65536 + 32768 + (h)*16384 + tid * 16);        \
    GLL16(sb + (size_t)((h)*128 + 64) * 4096 + (ko),                       \
          (char*)smem + (db)*65536 + 32768 + (h)*16384 + 8192 + tid * 16); \
  }

__device__ __forceinline__ unsigned int f2b(float f) {
  unsigned int u = __builtin_bit_cast(unsigned int, f);
  u += 0x7FFFu + ((u >> 16) & 1u);
  return u >> 16;
}

// ---------------------------------------------------------------------------
// Prep (single launch; measured ~43us ~= roofline):
//  blocks [0, 8192):    convert x -> bf16 (16 elems/thread)
//  blocks [8192, 11264): fold W' = W + B@A with LDS-shared A-tiles
// ---------------------------------------------------------------------------
__global__ void prep_kernel(const float* __restrict__ x,
                            const float* __restrict__ w0,
                            const float* __restrict__ w1,
                            const float* __restrict__ w2,
                            const float* __restrict__ a0,
                            const float* __restrict__ b0,
                            const float* __restrict__ a1,
                            const float* __restrict__ b1,
                            const float* __restrict__ a2,
                            const float* __restrict__ b2,
                            unsigned short* __restrict__ xb,
                            unsigned short* __restrict__ wb) {
  __shared__ float As[16][512];  // 32 KB
  const int bid = blockIdx.x;
  const int tid = threadIdx.x;
  if (bid < 8192) {
    long base = ((long)bid * 256 + tid) * 2;
    const float4* xp = reinterpret_cast<const float4*>(x) + base * 2;
#pragma unroll
    for (int j = 0; j < 2; ++j) {
      float4 v0 = xp[2 * j];
      float4 v1 = xp[2 * j + 1];
      uint4 o;
      o.x = f2b(v0.x) | (f2b(v0.y) << 16);
      o.y = f2b(v0.z) | (f2b(v0.w) << 16);
      o.z = f2b(v1.x) | (f2b(v1.y) << 16);
      o.w = f2b(v1.z) | (f2b(v1.w) << 16);
      reinterpret_cast<uint4*>(xb)[base + j] = o;
    }
  } else {
    const int fb = bid - 8192;          // 0..3071
    const int proj = fb >> 10;          // 0..2
    const int rem = fb & 1023;
    const int h0 = (rem >> 3) * 32;
    const int d0b = (rem & 7) * 512;
    const float* W = (proj == 0) ? w0 : ((proj == 1) ? w1 : w2);
    const float* Amat = (proj == 0) ? a0 : ((proj == 1) ? a1 : a2);
    const float* Bmat = (proj == 0) ? b0 : ((proj == 1) ? b1 : b2);
    unsigned short* Wo = wb + (size_t)proj * 16777216UL;

#pragma unroll
    for (int j = 0; j < 8; ++j) {
      int idx4 = tid + j * 256;
      int row = idx4 >> 7;
      int col4 = idx4 & 127;
      float4 v = *reinterpret_cast<const float4*>(
          Amat + (size_t)row * 4096 + d0b + col4 * 4);
      *reinterpret_cast<float4*>(&As[row][col4 * 4]) = v;
    }
    __syncthreads();

    const int hl = tid >> 3;
    const int dl = (tid & 7) * 8;
    const int h = h0 + hl;
    float bv[16];
#pragma unroll
    for (int r = 0; r < 16; ++r) bv[r] = Bmat[h * 16 + r];

#pragma unroll
    for (int c = 0; c < 8; ++c) {
      const int d = dl + c * 64;
      const float4* wp =
          reinterpret_cast<const float4*>(W + (size_t)h * 4096 + d0b + d);
      float4 w0v = wp[0], w1v = wp[1];
      float acc[8] = {w0v.x, w0v.y, w0v.z, w0v.w,
                      w1v.x, w1v.y, w1v.z, w1v.w};
#pragma unroll
      for (int r = 0; r < 16; ++r) {
        const float4 A0 = *reinterpret_cast<const float4*>(&As[r][d]);
        const float4 A1 = *reinterpret_cast<const float4*>(&As[r][d + 4]);
        acc[0] += bv[r] * A0.x; acc[1] += bv[r] * A0.y;
        acc[2] += bv[r] * A0.z; acc[3] += bv[r] * A0.w;
        acc[4] += bv[r] * A1.x; acc[5] += bv[r] * A1.y;
        acc[6] += bv[r] * A1.z; acc[7] += bv[r] * A1.w;
      }
      uint4 o;
      o.x = f2b(acc[0]) | (f2b(acc[1]) << 16);
      o.y = f2b(acc[2]) | (f2b(acc[3]) << 16);
      o.z = f2b(acc[4]) | (f2b(acc[5]) << 16);
      o.w = f2b(acc[6]) | (f2b(acc[7]) << 16);
      *reinterpret_cast<uint4*>(Wo + (size_t)h * 4096 + d0b + d) = o;
    }
  }
}

// ---------------------------------------------------------------------------
// GEMM: 256x256 tile, single-barrier 8-phase, balanced 4/8/4/8 reads.
//   C[M, N*3] = Xb[M,K] @ Wb[3][N,K]^T
// 512 threads = 8 waves (2M x 4N), wave tile 128x64. BK=64 (2 x K32).
// LDS 128 KiB = 2 dbuf x { A: 2 x 16KB halves | B: 2 x 16KB }, XOR-swizzled.
//
// Phase k = { BAR; lgkmcnt(0); 16 MFMA (setprio); reads_{k+1}; stages; [vm] }
// 8 barriers/iter: fast waves issue next-phase ds_reads while slow waves
// still run MFMAs -> LDS and matrix pipes overlap cross-wave.
// Split vm-guards: WVM(4)@ph2 drains D1.B -> bLo(buf1) readable at ph3;
// ph3's WVM(4) drains D1.A -> aLo at ph4; symmetric ph6/ph7. Reads/phase
// 4/8/4/8. bLo ping-pong (bLoA=buf0, bLoB=buf1).
//
// Collective-safety (per-wave counters closed by barriers):
//  reads: ph1(bHi,buf0)/ph2(aHi,buf0) <- prev ph7 WVM(4)+BAR8 / same
//         ph3(bLoB,buf1.B) <- ph2 WVM(4) [drains D1.B] < BAR3
//         ph4(aLo,buf1.A)  <- ph3 WVM(4) [drains D1.A] < BAR4
//         ph5(bHi,buf1)/ph6(aHi,buf1) <- same guards < BAR5/6
//         ph7(bLoA,buf0-next.B) <- ph6 WVM(4) [drains N0.B] < BAR7
//         ph8(aLo,buf0-next.A)  <- ph7 WVM(4) [drains N0.A] < BAR8
//         PROLOGUE (T0) <- WVM(4) < BAR < reads
//  stages: ph3 N0.B <- all-waves bHi drained (WLGS0@ph2) < BAR3
//          ph4 N0.A <- aLo(WLGS0@ph1), aHi(WLGS0@ph3) < BAR4
//          ph7 N1.B <- bLoB(WLGS0@ph4), bHi(WLGS0@ph6) < BAR7
//          ph8 N1.A <- aLo(ph5), aHi(ph7) < BAR8
// vmcnt ledger (4 loads per stage-group): entering ph1 out=8; ph2 WVM(4)
//  drains D1.B; ph3 +N0.B=8, WVM(4) drains D1.A; ph4 +N0.A=8; ph6 WVM(4)
//  drains N0.B; ph7 +N1.B=8, WVM(4) drains N0.A; ph8 +N1.A=8.
//  Tail i=31: ph3 else-WVM(0); ph7/ph8 st-gated.
// ---------------------------------------------------------------------------
__global__ __launch_bounds__(512, 2) void gemm_kernel(
    const unsigned short* __restrict__ Xb,
    const unsigned short* __restrict__ Wb, float* __restrict__ out) {
  __shared__ unsigned short smem[65536];  // 128 KiB

  const int tid = threadIdx.x;
  const int lane = tid & 63;
  const int wid = tid >> 6;
  const int wm = wid >> 2;  // 0..1
  const int wn = wid & 3;   // 0..3

  int bid = blockIdx.x;                    // 1536 = 3 proj * 32 brow * 16 bcol
  int swz = (bid & 7) * 192 + (bid >> 3);  // bijective XCD swizzle
  int p = swz >> 9;
  int r = swz & 511;
  int brow = r >> 4;  // 0..31
  int bcol = r & 15;  // 0..15

  const unsigned short* GA = Xb + (size_t)brow * 256 * 4096;
  const unsigned short* GB =
      Wb + (size_t)p * 16777216UL + (size_t)bcol * 256 * 4096;

  // staging source, pre-swizzled so LDS[r][s] holds global[r][s^(r&7)]
  const int srow = tid >> 3;
  const int sslot = (tid & 7) ^ (srow & 7);
  const unsigned short* sa = GA + (size_t)srow * 4096 + sslot * 8;
  const unsigned short* sb = GB + (size_t)srow * 4096 + sslot * 8;

  // fragment-read bases (element units), swizzled k-slot offsets
  const int lrow = lane & 15;
  const int g = lane >> 4;  // 0..3
  const int swk0 = (g ^ (lane & 7)) * 8;
  const int swk1 = ((4 + g) ^ (lane & 7)) * 8;
  const __bf16* sm = (const __bf16*)smem;
  const __bf16* arA0 = sm + wm * 8192 + lrow * 64;
  const __bf16* arB0 =
      sm + 16384 + (wn >> 1) * 8192 + ((wn & 1) * 64 + lrow) * 64;
  const __bf16* arA1 = arA0 + 32768;
  const __bf16* arB1 = arB0 + 32768;

  f32x4 acc[8][4];
#pragma unroll
  for (int m = 0; m < 8; ++m)
#pragma unroll
    for (int n = 0; n < 4; ++n) acc[m][n] = {0.f, 0.f, 0.f, 0.f};

  bf16x8 aLo[2][4], aHi[2][4], bLoA[2][2], bLoB[2][2], bHi[2][2];

  // prologue: T0 full + T1.B (12 loads); own-drain T0; collective barrier;
  // then T0 q00 reads (aLo + bLoA) + T1.A stages (outstanding -> 8).
  STG_B(0, 0, 0); STG_B(0, 1, 0); STG_A(0, 0, 0); STG_A(0, 1, 0);
  STG_B(1, 0, 64); STG_B(1, 1, 64);
  WVM(4);  // own T0 landed; T1.B in flight
  BAR();   // ALL waves' T0 landed
  RDA(aLo, arA0, 0);
  RDB(bLoA, arB0, 0);
  STG_A(1, 0, 64); STG_A(1, 1, 64);  // out = T1.B(4) + T1.A(4) = 8

  for (int i = 0; i < 32; ++i) {
    const bool st = (i < 31);
    const size_t koN0 = (size_t)(2 * i + 2) * 64;
    const size_t koN1 = (size_t)(2 * i + 3) * 64;

    // ph1: q00(buf0); read bHi(buf0)        [4 reads]
    BAR();
    WLGS(0);
    MFQ(aLo, bLoA, 0, 0);
    RDB(bHi, arB0, 2);
    // ph2: q01(buf0); read aHi(buf0); guard D1.B  [8 reads]
    BAR();
    WLGS(0);
    MFQ(aLo, bHi, 0, 2);
    RDA(aHi, arA0, 4);
    WVM(4);
    // ph3: q11(buf0); read bLoB(buf1.B, safe after BAR3); stage N0.B;
    //      guard D1.A                        [4 reads]
    BAR();
    WLGS(0);
    MFQ(aHi, bHi, 4, 2);
    RDB(bLoB, arB1, 0);
    if (st) {
      STG_B(0, 0, koN0);
      STG_B(0, 1, koN0);
      WVM(4);
    } else {
      WVM(0);
    }
    // ph4: q10(buf0); read aLo(buf1.A, safe after BAR4); stage N0.A [8 reads]
    BAR();
    WLGS(0);
    MFQ(aHi, bLoA, 4, 0);
    RDA(aLo, arA1, 0);
    if (st) {
      STG_A(0, 0, koN0);
      STG_A(0, 1, koN0);
    }
    // ph5: q00(buf1); read bHi(buf1)        [4 reads]
    BAR();
    WLGS(0);
    MFQ(aLo, bLoB, 0, 0);
    RDB(bHi, arB1, 2);
    // ph6: q01(buf1); read aHi(buf1); guard N0.B  [8 reads]
    BAR();
    WLGS(0);
    MFQ(aLo, bHi, 0, 2);
    RDA(aHi, arA1, 4);
    WVM(4);
    // ph7: q11(buf1); read bLoA(buf0-next.B, safe after BAR7); stage N1.B;
    //      guard N0.A                       [4 reads]
    BAR();
    WLGS(0);
    MFQ(aHi, bHi, 4, 2);
    if (st) {
      RDB(bLoA, arB0, 0);
      STG_B(1, 0, koN1);
      STG_B(1, 1, koN1);
      WVM(4);
    }
    // ph8: q10(buf1); read aLo(buf0-next.A); stage N1.A  [8 reads]
    BAR();
    WLGS(0);
    MFQ(aHi, bLoB, 4, 0);
    if (st) {
      RDA(aLo, arA0, 0);
      STG_A(1, 0, koN1);
      STG_A(1, 1, koN1);
    }
  }

  // epilogue: C/D layout col = lane&15, row = (lane>>4)*4 + q
  float* Cp = out + (size_t)p * 33554432UL +
              ((size_t)(brow * 256 + wm * 128 + g * 4)) * 4096 +
              (bcol * 256 + wn * 64 + lrow);
#pragma unroll
  for (int m = 0; m < 8; ++m)
#pragma unroll
    for (int q = 0; q < 4; ++q) {
      float* rp = Cp + (size_t)(m * 16 + q) * 4096;
#pragma unroll
      for (int n = 0; n < 4; ++n) rp[n * 16] = acc[m][n][q];
    }
}

// ---------------------------------------------------------------------------
extern "C" void kernel_launch(void* const* d_in, const int* in_sizes, int n_in,
                              void* d_out, int out_size, void* d_ws,
                              size_t ws_size, hipStream_t stream) {
  const float* x = (const float*)d_in[0];
  const float* wq = (const float*)d_in[1];
  const float* wk = (const float*)d_in[2];
  const float* wv = (const float*)d_in[3];
  const float* qa = (const float*)d_in[4];
  const float* qb = (const float*)d_in[5];
  const float* ka = (const float*)d_in[6];
  const float* kb = (const float*)d_in[7];
  const float* va = (const float*)d_in[8];
  const float* vb = (const float*)d_in[9];

  unsigned short* xb = (unsigned short*)d_ws;  // 67 MB
  unsigned short* wb = xb + 8192UL * 4096UL;   // 100 MB

  prep_kernel<<<11264, 256, 0, stream>>>(x, wq, wk, wv, qa, qb, ka, kb, va,
                                         vb, xb, wb);
  gemm_kernel<<<1536, 512, 0, stream>>>(xb, wb, (float*)d_out);
}